// Round 2
// baseline (1780.371 us; speedup 1.0000x reference)
//
#include <hip/hip_runtime.h>

#define LROWS 8
#define MCOLS 8
#define BD 32
#define NSITE 64
#define SPB 64          // samples per block (one wave per role)
#define EPS 1e-10
#define PI_D 3.14159265358979323846

// ws layout (in DOUBLES):
//  Wbuf : [64 sites][4 roles][32 b][32]  = 262144 doubles (Mh half | Mv half per b-row)
//  Cbuf : [64 sites][4 roles][48]        = 12288 doubles  (v16 | eta2_16 | w16)
//  Ccbuf: [64 sites]                     = 64 doubles     (c scalar)
#define WBUF_OFF 0
#define CBUF_OFF 262144
#define CCBUF_OFF (262144 + 12288)
#define WS_DBLS (262144 + 12288 + 64)

__global__ void precompute_kernel(const float* __restrict__ M_h,
                                  const float* __restrict__ M_v,
                                  const float* __restrict__ v,
                                  const float* __restrict__ w,
                                  const float* __restrict__ cc,
                                  const float* __restrict__ eta,
                                  double* __restrict__ ws) {
    int idx = blockIdx.x * 256 + threadIdx.x;
    if (idx < 262144) {
        // Wbuf
        int t = idx & 31, b = (idx >> 5) & 31, r = (idx >> 10) & 3, site = idx >> 12;
        int i = site >> 3, js = site & 7;
        int c = (i & 1) ? (MCOLS - 1 - js) : js;
        int s = r >> 1, abase = (r & 1) * 16;
        float val;
        if (t < 16) {
            int a = abase + t;
            val = M_h[(((i * MCOLS + c) * 2 + s) * BD + a) * BD + b];
        } else {
            int a = abase + (t - 16);
            val = M_v[(((i * MCOLS + c) * 2 + s) * BD + a) * BD + b];
        }
        ws[WBUF_OFF + idx] = (double)val;
    } else if (idx < 262144 + 12288) {
        int j = idx - 262144;
        int t = j % 48;
        int r = (j / 48) & 3;
        int site = j / 192;
        int i = site >> 3, js = site & 7;
        int c = (i & 1) ? (MCOLS - 1 - js) : js;
        int s = r >> 1, abase = (r & 1) * 16;
        double val;
        if (t < 16) {
            val = (double)v[(((i * MCOLS + c) * 2 + s) * BD) + abase + t];
        } else if (t < 32) {
            double e = (double)eta[(i * MCOLS + c) * BD + abase + (t - 16)];
            val = e * e;
        } else {
            val = (double)w[(i * MCOLS + c) * BD + abase + (t - 32)];
        }
        ws[CBUF_OFF + j] = val;
    } else if (idx < WS_DBLS) {
        int site = idx - (262144 + 12288);
        int i = site >> 3, js = site & 7;
        int c = (i & 1) ? (MCOLS - 1 - js) : js;
        ws[CCBUF_OFF + site] = (double)cc[i * MCOLS + c];
    }
}

__launch_bounds__(256, 1)
__global__ void mps_main_kernel(const int* __restrict__ x,
                                const double* __restrict__ ws,
                                float* __restrict__ out) {
    __shared__ double hRow[MCOLS][BD][SPB];  // 128 KB, lattice-column indexed
    __shared__ double pbuf[4][SPB];          // 2 KB
    __shared__ double ssbuf[2][SPB];         // 1 KB
    __shared__ double phbuf[2][SPB];         // 1 KB

    const int tid = threadIdx.x;
    const int k = tid & 63;               // sample within block (lane)
    const int r = tid >> 6;               // role: (s<<1)|half, wave-uniform
    const int r_u = __builtin_amdgcn_readfirstlane(r);
    const int s = r_u >> 1;
    const int abase = (r_u & 1) * 16;
    const int kg = blockIdx.x * SPB + k;  // global sample

    // bottom boundary = zeros
    {
        double* p = &hRow[0][0][0];
        for (int t = tid; t < MCOLS * BD * SPB; t += 256) p[t] = 0.0;
    }
    __syncthreads();

    const double* __restrict__ Wb = ws + WBUF_OFF;
    const double* __restrict__ Cb = ws + CBUF_OFF;
    const double* __restrict__ Cc = ws + CCBUF_OFF;

    double la = 0.0, ph = 0.0;

    for (int i = 0; i < LROWS; ++i) {
        // pack this row's occupations (scan order == qubit order)
        const int* xp = x + (size_t)kg * NSITE + i * MCOLS;
        int4 xa = *reinterpret_cast<const int4*>(xp);
        int4 xb = *reinterpret_cast<const int4*>(xp + 4);
        unsigned xbits = (unsigned)((xa.x & 1)        | ((xa.y & 1) << 1) |
                                    ((xa.z & 1) << 2) | ((xa.w & 1) << 3) |
                                    ((xb.x & 1) << 4) | ((xb.y & 1) << 5) |
                                    ((xb.z & 1) << 6) | ((xb.w & 1) << 7));
        for (int js = 0; js < MCOLS; ++js) {
            const int site = i * MCOLS + js;
            const int c = (i & 1) ? (MCOLS - 1 - js) : js;        // lattice col (scan pos js)
            const int cprev = (i & 1) ? (MCOLS - js) : (js - 1);  // lattice col of scan pos js-1

            const double* __restrict__ cb = Cb + (size_t)(site * 4 + r_u) * 48;
            const double* __restrict__ wb = Wb + (size_t)(site * 4 + r_u) * 1024;

            double acc[16];
            #pragma unroll
            for (int a = 0; a < 16; ++a) acc[a] = cb[a];  // v bias

            if (js == 0) {
                #pragma unroll 4
                for (int b = 0; b < BD; ++b) {
                    const double hvb = hRow[c][b][k];
                    const double* __restrict__ wr = wb + b * 32;
                    #pragma unroll
                    for (int a = 0; a < 16; ++a)
                        acc[a] = fma(wr[16 + a], hvb, acc[a] + wr[a]);  // hl = 1.0
                }
            } else {
                #pragma unroll 4
                for (int b = 0; b < BD; ++b) {
                    const double hlb = hRow[cprev][b][k];
                    const double hvb = hRow[c][b][k];
                    const double* __restrict__ wr = wb + b * 32;
                    #pragma unroll
                    for (int a = 0; a < 16; ++a)
                        acc[a] = fma(wr[a], hlb, fma(wr[16 + a], hvb, acc[a]));
                }
            }

            // eta-weighted prob partial + plain sumsq partial over this half
            double pp = 0.0, ssp = 0.0;
            #pragma unroll
            for (int a = 0; a < 16; ++a) {
                double t2 = acc[a] * acc[a];
                pp = fma(t2, cb[16 + a], pp);
                ssp += t2;
            }
            const int xs = (int)((xbits >> js) & 1u);
            const bool sel = (s == xs);
            pbuf[r][k] = pp;
            if (sel) ssbuf[r & 1][k] = ssp;
            __syncthreads();

            const double p0 = pbuf[0][k] + pbuf[1][k];
            const double p1 = pbuf[2][k] + pbuf[3][k];
            const double psel = xs ? p1 : p0;
            la += 0.5 * (log(psel + EPS) - log(p0 + p1 + EPS));

            const double ss = ssbuf[0][k] + ssbuf[1][k];
            const double inv = 1.0 / (sqrt(ss) + EPS);
            if (sel) {
                double php = 0.0;
                #pragma unroll
                for (int a = 0; a < 16; ++a) {
                    double hn = acc[a] * inv;
                    hRow[c][abase + a][k] = hn;   // h_left of next site & h_below of next row
                    php = fma(hn, cb[32 + a], php);
                }
                phbuf[r & 1][k] = php;
            }
            __syncthreads();

            const double aph = phbuf[0][k] + phbuf[1][k] + Cc[site];
            ph += (aph < 0.0) ? PI_D : 0.0;
        }
    }

    if (r == 0) {
        out[(size_t)kg * 2]     = (float)la;
        out[(size_t)kg * 2 + 1] = (float)ph;
    }
}

extern "C" void kernel_launch(void* const* d_in, const int* in_sizes, int n_in,
                              void* d_out, int out_size, void* d_ws, size_t ws_size,
                              hipStream_t stream) {
    const int*   x    = (const int*)d_in[0];
    const float* M_h  = (const float*)d_in[1];
    const float* M_v  = (const float*)d_in[2];
    const float* v    = (const float*)d_in[3];
    const float* w    = (const float*)d_in[4];
    const float* cc   = (const float*)d_in[5];
    const float* eta  = (const float*)d_in[6];
    float* out = (float*)d_out;
    double* ws = (double*)d_ws;

    const int pre_total = WS_DBLS;
    dim3 preGrid((pre_total + 255) / 256), preBlock(256);
    hipLaunchKernelGGL(precompute_kernel, preGrid, preBlock, 0, stream,
                       M_h, M_v, v, w, cc, eta, ws);

    const int B = 32768;
    dim3 grid(B / SPB), block(256);
    hipLaunchKernelGGL(mps_main_kernel, grid, block, 0, stream, x, ws, out);
}

// Round 3
// 1600.700 us; speedup vs baseline: 1.1122x; 1.1122x over previous
//
#include <hip/hip_runtime.h>

#define LROWS 8
#define MCOLS 8
#define BD 32
#define NSITE 64
#define SPB 60            // samples per block (lanes 60-63 idle for compute, help staging)
#define BTOT 32768
#define NBLK ((BTOT + SPB - 1) / SPB)   // 547
#define EPS 1e-10
#define PI_D 3.14159265358979323846

// Per-site staged block (SiteBlk), in doubles:
//   [0 .. 4095]    W[role][b][t] : t<16 -> Mh[abase+t][b], t>=16 -> Mv[abase+t-16][b]
//   [4096 .. 4287] CB[role][48]  : v[16] | eta^2[16] | w[16]
//   [4288]         c scalar        [4289] pad (16B alignment)
#define SB_DBL 4290
#define SB_BYTES (SB_DBL * 8)           // 34320
#define SB_CHUNKS ((SB_BYTES + 1023) / 1024)  // 34 chunks of 1024 B (64 lanes x 16 B)

__global__ void precompute_kernel(const float* __restrict__ M_h,
                                  const float* __restrict__ M_v,
                                  const float* __restrict__ v,
                                  const float* __restrict__ w,
                                  const float* __restrict__ cc,
                                  const float* __restrict__ eta,
                                  double* __restrict__ ws) {
    int idx = blockIdx.x * 256 + threadIdx.x;
    if (idx >= NSITE * SB_DBL) return;
    int site = idx / SB_DBL;
    int off  = idx - site * SB_DBL;
    int i = site >> 3, js = site & 7;
    int c = (i & 1) ? (MCOLS - 1 - js) : js;
    double val = 0.0;
    if (off < 4096) {
        int t = off & 31, b = (off >> 5) & 31, r = off >> 10;
        int s = r >> 1, abase = (r & 1) * 16;
        if (t < 16) val = (double)M_h[(((i * MCOLS + c) * 2 + s) * BD + (abase + t)) * BD + b];
        else        val = (double)M_v[(((i * MCOLS + c) * 2 + s) * BD + (abase + t - 16)) * BD + b];
    } else if (off < 4288) {
        int j = off - 4096;
        int r = j / 48, t = j - r * 48;
        int s = r >> 1, abase = (r & 1) * 16;
        if (t < 16)      val = (double)v[(((i * MCOLS + c) * 2 + s) * BD) + abase + t];
        else if (t < 32) { double e = (double)eta[(i * MCOLS + c) * BD + abase + (t - 16)]; val = e * e; }
        else             val = (double)w[(i * MCOLS + c) * BD + abase + (t - 32)];
    } else if (off == 4288) {
        val = (double)cc[i * MCOLS + c];
    }
    ws[idx] = val;
}

__launch_bounds__(256, 1)
__global__ void mps_main_kernel(const int* __restrict__ x,
                                const double* __restrict__ ws,
                                float* __restrict__ out) {
    __shared__ double hRow[MCOLS][BD][SPB];   // 122880 B, lattice-column indexed
    __shared__ double wbuf[SB_DBL];           // 34320 B, current site's weights
    __shared__ double pbuf[4][64];            // 2 KB
    __shared__ double ssbuf[2][64];           // 1 KB
    __shared__ double phbuf[2][64];           // 1 KB

    const int tid = threadIdx.x;
    const int k = tid & 63;                 // lane = sample slot
    const int r = tid >> 6;                 // role: (s<<1)|a-half, wave-uniform
    const int r_u = __builtin_amdgcn_readfirstlane(r);
    const int s = r_u >> 1;
    const int abase = (r_u & 1) * 16;
    const int kk = (k < SPB) ? k : 0;       // clamped sample index for LDS reads
    const long kg = (long)blockIdx.x * SPB + k;
    const bool live = (k < SPB) && (kg < (long)BTOT);

    // zero hRow (bottom boundary)
    for (int t = tid; t < MCOLS * BD * SPB; t += 256) (&hRow[0][0][0])[t] = 0.0;

    // ---- async stage of one site's weight block into LDS ----
    // chunk = 1024 B (64 lanes x 16 B); wave w takes chunks w, w+4, ...
#define STAGE_SITE(ST)                                                          \
    do {                                                                        \
        const char* gsb = (const char*)(ws + (size_t)(ST) * SB_DBL);            \
        for (int cch = r_u; cch < SB_CHUNKS; cch += 4) {                        \
            int byteoff = cch << 10;                                            \
            int lb = byteoff + (k << 4);                                        \
            if (lb < SB_BYTES) {                                                \
                __builtin_amdgcn_global_load_lds(                               \
                    (const __attribute__((address_space(1))) void*)(gsb + lb),  \
                    (__attribute__((address_space(3))) void*)((char*)&wbuf[0] + byteoff), \
                    16, 0, 0);                                                  \
            }                                                                   \
        }                                                                       \
    } while (0)

    STAGE_SITE(0);
    __syncthreads();   // drains vmcnt: site-0 weights + hRow zeros visible

    double la = 0.0, ph = 0.0;

    for (int i = 0; i < LROWS; ++i) {
        unsigned xbits = 0;
        if (live) {
            const int* xp = x + kg * NSITE + i * MCOLS;
            int4 xa = *reinterpret_cast<const int4*>(xp);
            int4 xb = *reinterpret_cast<const int4*>(xp + 4);
            xbits = (unsigned)((xa.x & 1)        | ((xa.y & 1) << 1) |
                               ((xa.z & 1) << 2) | ((xa.w & 1) << 3) |
                               ((xb.x & 1) << 4) | ((xb.y & 1) << 5) |
                               ((xb.z & 1) << 6) | ((xb.w & 1) << 7));
        }
        double prodN = 1.0, prodD = 1.0;

        for (int js = 0; js < MCOLS; ++js) {
            const int site = i * MCOLS + js;
            const int c = (i & 1) ? (MCOLS - 1 - js) : js;
            const int cprev = (i & 1) ? (MCOLS - js) : (js - 1);

            const double* __restrict__ cb    = &wbuf[4096 + r_u * 48];
            const double* __restrict__ wrole = &wbuf[r_u * 1024];

            double acc[16];
            #pragma unroll
            for (int a = 0; a < 16; ++a) acc[a] = cb[a];   // v bias

            if (js == 0) {
                #pragma unroll 2
                for (int b = 0; b < BD; ++b) {
                    const double hvb = hRow[c][b][kk];
                    const double* __restrict__ wr = wrole + b * 32;
                    #pragma unroll
                    for (int a = 0; a < 16; ++a)
                        acc[a] = fma(wr[16 + a], hvb, acc[a] + wr[a]);   // h_left = 1
                }
            } else {
                #pragma unroll 2
                for (int b = 0; b < BD; ++b) {
                    const double hlb = hRow[cprev][b][kk];
                    const double hvb = hRow[c][b][kk];
                    const double* __restrict__ wr = wrole + b * 32;
                    #pragma unroll
                    for (int a = 0; a < 16; ++a)
                        acc[a] = fma(wr[a], hlb, fma(wr[16 + a], hvb, acc[a]));
                }
            }

            // partials: eta-weighted prob, plain sumsq, unnormalized phase dot
            double pp = 0.0, ssp = 0.0, phr = 0.0;
            #pragma unroll
            for (int a = 0; a < 16; ++a) {
                const double t2 = acc[a] * acc[a];
                pp  = fma(t2, cb[16 + a], pp);
                ssp += t2;
                phr = fma(acc[a], cb[32 + a], phr);
            }
            const double ccoef = wbuf[4288];     // read BEFORE staging overwrites wbuf
            const int xs = (int)((xbits >> js) & 1u);
            const bool sel = (s == xs);

            pbuf[r][k] = pp;
            if (sel) { ssbuf[r & 1][k] = ssp; phbuf[r & 1][k] = phr; }
            __syncthreads();   // barrier1: wbuf reads complete, partials visible

            // async prefetch of next site's weights (overlaps phase-finish)
            if (site + 1 < NSITE) STAGE_SITE(site + 1);

            const double p0 = pbuf[0][k] + pbuf[1][k];
            const double p1 = pbuf[2][k] + pbuf[3][k];
            const double psel = xs ? p1 : p0;
            prodN *= (psel + EPS);
            prodD *= (p0 + p1 + EPS);

            const double ss  = ssbuf[0][k] + ssbuf[1][k];
            const double inv = 1.0 / (sqrt(ss) + EPS);
            if (sel && k < SPB) {
                #pragma unroll
                for (int a = 0; a < 16; ++a)
                    hRow[c][abase + a][k] = acc[a] * inv;   // h_left next site / h_below next row
            }
            const double aph = (phbuf[0][k] + phbuf[1][k]) * inv + ccoef;
            ph += (aph < 0.0) ? PI_D : 0.0;

            __syncthreads();   // barrier2: hRow updated + staging drained (vmcnt 0)
        }
        la += 0.5 * (log(prodN) - log(prodD));
    }

    if (r == 0 && live) {
        out[kg * 2]     = (float)la;
        out[kg * 2 + 1] = (float)ph;
    }
#undef STAGE_SITE
}

extern "C" void kernel_launch(void* const* d_in, const int* in_sizes, int n_in,
                              void* d_out, int out_size, void* d_ws, size_t ws_size,
                              hipStream_t stream) {
    const int*   x    = (const int*)d_in[0];
    const float* M_h  = (const float*)d_in[1];
    const float* M_v  = (const float*)d_in[2];
    const float* v    = (const float*)d_in[3];
    const float* w    = (const float*)d_in[4];
    const float* cc   = (const float*)d_in[5];
    const float* eta  = (const float*)d_in[6];
    float* out = (float*)d_out;
    double* ws = (double*)d_ws;

    const int pre_total = NSITE * SB_DBL;
    dim3 preGrid((pre_total + 255) / 256), preBlock(256);
    hipLaunchKernelGGL(precompute_kernel, preGrid, preBlock, 0, stream,
                       M_h, M_v, v, w, cc, eta, ws);

    dim3 grid(NBLK), block(256);
    hipLaunchKernelGGL(mps_main_kernel, grid, block, 0, stream, x, ws, out);
}

// Round 4
// 1518.972 us; speedup vs baseline: 1.1721x; 1.0538x over previous
//
#include <hip/hip_runtime.h>

#define LROWS 8
#define MCOLS 8
#define BD 32
#define NSITE 64
#define SPB 64            // samples per block, all lanes live
#define BTOT 32768
#define NBLK (BTOT / SPB)               // 512 = exactly 2 occupancy rounds on 256 CUs
#define EPS 1e-10
#define PI_D 3.14159265358979323846

// Per-site staged block (fp32), in floats:
//   [0 .. 4095]    W[role][b][t] : t<16 -> Mh[abase+t][b], t>=16 -> Mv[abase+t-16][b]
//   [4096 .. 4287] CB[role][48]  : v[16] | eta_raw[16] | w[16]
//   [4288]         c scalar;  [4289..4351] pad
#define SB_FLOATS 4352
#define SB_BYTES (SB_FLOATS * 4)        // 17408 = 17 chunks of 1024 B
#define SB_CHUNKS 17

__global__ void precompute_kernel(const float* __restrict__ M_h,
                                  const float* __restrict__ M_v,
                                  const float* __restrict__ v,
                                  const float* __restrict__ w,
                                  const float* __restrict__ cc,
                                  const float* __restrict__ eta,
                                  float* __restrict__ ws) {
    int idx = blockIdx.x * 256 + threadIdx.x;
    if (idx >= NSITE * SB_FLOATS) return;
    int site = idx / SB_FLOATS;
    int off  = idx - site * SB_FLOATS;
    int i = site >> 3, js = site & 7;
    int c = (i & 1) ? (MCOLS - 1 - js) : js;
    float val = 0.f;
    if (off < 4096) {
        int t = off & 31, b = (off >> 5) & 31, r = off >> 10;
        int s = r >> 1, abase = (r & 1) * 16;
        if (t < 16) val = M_h[(((i * MCOLS + c) * 2 + s) * BD + (abase + t)) * BD + b];
        else        val = M_v[(((i * MCOLS + c) * 2 + s) * BD + (abase + t - 16)) * BD + b];
    } else if (off < 4288) {
        int j = off - 4096;
        int r = j / 48, t = j - r * 48;
        int s = r >> 1, abase = (r & 1) * 16;
        if (t < 16)      val = v[(((i * MCOLS + c) * 2 + s) * BD) + abase + t];
        else if (t < 32) val = eta[(i * MCOLS + c) * BD + abase + (t - 16)];   // raw eta; squared in fp64 on device
        else             val = w[(i * MCOLS + c) * BD + abase + (t - 32)];
    } else if (off == 4288) {
        val = cc[i * MCOLS + c];
    }
    ws[idx] = val;
}

__launch_bounds__(256, 1)
__global__ void mps_main_kernel(const int* __restrict__ x,
                                const float* __restrict__ ws,
                                float* __restrict__ out) {
    __shared__ double hRow[MCOLS][BD][SPB];          // 131072 B
    __shared__ __align__(16) float wbuf[SB_FLOATS];  // 17408 B
    __shared__ double pbuf[4][64];                   // 2 KB
    __shared__ double ssbuf[2][64];                  // 1 KB
    __shared__ double phbuf[2][64];                  // 1 KB

    const int tid = threadIdx.x;
    const int k = tid & 63;                 // lane = sample slot
    const int r = tid >> 6;                 // role: (s<<1)|a-half, wave-uniform
    const int r_u = __builtin_amdgcn_readfirstlane(r);
    const int s = r_u >> 1;
    const int abase = (r_u & 1) * 16;
    const long kg = (long)blockIdx.x * SPB + k;

    // zero hRow (bottom boundary)
    for (int t = tid; t < MCOLS * BD * SPB; t += 256) (&hRow[0][0][0])[t] = 0.0;

    // ---- async stage of one site's fp32 weight block into LDS ----
#define STAGE_SITE(ST)                                                          \
    do {                                                                        \
        const char* gsb = (const char*)(ws + (size_t)(ST) * SB_FLOATS);         \
        for (int cch = r_u; cch < SB_CHUNKS; cch += 4) {                        \
            int byteoff = cch << 10;                                            \
            __builtin_amdgcn_global_load_lds(                                   \
                (const __attribute__((address_space(1))) void*)(gsb + byteoff + (k << 4)), \
                (__attribute__((address_space(3))) void*)((char*)&wbuf[0] + byteoff), \
                16, 0, 0);                                                      \
        }                                                                       \
    } while (0)

    STAGE_SITE(0);
    __syncthreads();   // drains vmcnt: site-0 weights + hRow zeros visible

    double la = 0.0, ph = 0.0;

    for (int i = 0; i < LROWS; ++i) {
        const int* xp = x + kg * NSITE + i * MCOLS;
        int4 xa = *reinterpret_cast<const int4*>(xp);
        int4 xb = *reinterpret_cast<const int4*>(xp + 4);
        const unsigned xbits = (unsigned)((xa.x & 1)        | ((xa.y & 1) << 1) |
                                          ((xa.z & 1) << 2) | ((xa.w & 1) << 3) |
                                          ((xb.x & 1) << 4) | ((xb.y & 1) << 5) |
                                          ((xb.z & 1) << 6) | ((xb.w & 1) << 7));
        double prodN = 1.0, prodD = 1.0;

        for (int js = 0; js < MCOLS; ++js) {
            const int site = i * MCOLS + js;
            const int c = (i & 1) ? (MCOLS - 1 - js) : js;
            const int cprev = (i & 1) ? (MCOLS - js) : (js - 1);

            const float* __restrict__ cb    = &wbuf[4096 + r_u * 48];
            const float* __restrict__ wrole = &wbuf[r_u * 1024];

            double acc[16];
            #pragma unroll
            for (int a = 0; a < 16; ++a) acc[a] = (double)cb[a];   // v bias (exact cast)

            if (js == 0) {
                #pragma unroll 4
                for (int b = 0; b < BD; ++b) {
                    const double hvb = hRow[c][b][k];
                    const float* __restrict__ wr = wrole + b * 32;
                    #pragma unroll
                    for (int a = 0; a < 16; ++a)
                        acc[a] = fma((double)wr[16 + a], hvb, acc[a] + (double)wr[a]);  // h_left = 1
                }
            } else {
                #pragma unroll 4
                for (int b = 0; b < BD; ++b) {
                    const double hlb = hRow[cprev][b][k];
                    const double hvb = hRow[c][b][k];
                    const float* __restrict__ wr = wrole + b * 32;
                    #pragma unroll
                    for (int a = 0; a < 16; ++a)
                        acc[a] = fma((double)wr[a], hlb, fma((double)wr[16 + a], hvb, acc[a]));
                }
            }

            // partials: eta-weighted prob, plain sumsq, unnormalized phase dot
            double pp = 0.0, ssp = 0.0, phr = 0.0;
            #pragma unroll
            for (int a = 0; a < 16; ++a) {
                const double t2 = acc[a] * acc[a];
                const double e = (double)cb[16 + a];
                pp  = fma(t2, e * e, pp);            // eta squared in fp64 (matches np)
                ssp += t2;
                phr = fma(acc[a], (double)cb[32 + a], phr);
            }
            const double ccoef = (double)wbuf[4288];  // read BEFORE staging overwrites wbuf
            const int xs = (int)((xbits >> js) & 1u);
            const bool sel = (s == xs);

            pbuf[r][k] = pp;
            if (sel) { ssbuf[r & 1][k] = ssp; phbuf[r & 1][k] = phr; }
            __syncthreads();   // barrier1: wbuf reads complete, partials visible

            // async prefetch of next site's weights (overlaps phase-finish)
            if (site + 1 < NSITE) STAGE_SITE(site + 1);

            const double p0 = pbuf[0][k] + pbuf[1][k];
            const double p1 = pbuf[2][k] + pbuf[3][k];
            const double psel = xs ? p1 : p0;
            prodN *= (psel + EPS);
            prodD *= (p0 + p1 + EPS);

            const double ss  = ssbuf[0][k] + ssbuf[1][k];
            const double inv = 1.0 / (sqrt(ss) + EPS);
            if (sel) {
                #pragma unroll
                for (int a = 0; a < 16; ++a)
                    hRow[c][abase + a][k] = acc[a] * inv;   // h_left next site / h_below next row
            }
            const double aph = (phbuf[0][k] + phbuf[1][k]) * inv + ccoef;
            ph += (aph < 0.0) ? PI_D : 0.0;

            __syncthreads();   // barrier2: hRow updated + staging drained (vmcnt 0)
        }
        la += 0.5 * (log(prodN) - log(prodD));
    }

    if (r == 0) {
        out[kg * 2]     = (float)la;
        out[kg * 2 + 1] = (float)ph;
    }
#undef STAGE_SITE
}

extern "C" void kernel_launch(void* const* d_in, const int* in_sizes, int n_in,
                              void* d_out, int out_size, void* d_ws, size_t ws_size,
                              hipStream_t stream) {
    const int*   x    = (const int*)d_in[0];
    const float* M_h  = (const float*)d_in[1];
    const float* M_v  = (const float*)d_in[2];
    const float* v    = (const float*)d_in[3];
    const float* w    = (const float*)d_in[4];
    const float* cc   = (const float*)d_in[5];
    const float* eta  = (const float*)d_in[6];
    float* out = (float*)d_out;
    float* ws  = (float*)d_ws;

    const int pre_total = NSITE * SB_FLOATS;
    dim3 preGrid((pre_total + 255) / 256), preBlock(256);
    hipLaunchKernelGGL(precompute_kernel, preGrid, preBlock, 0, stream,
                       M_h, M_v, v, w, cc, eta, ws);

    dim3 grid(NBLK), block(256);
    hipLaunchKernelGGL(mps_main_kernel, grid, block, 0, stream, x, ws, out);
}